// Round 11
// baseline (82.774 us; speedup 1.0000x reference)
//
#include <hip/hip_runtime.h>
#include <hip/hip_bf16.h>

// SPQR dequant-GEMV via MFMA: y = x @ Wd^T + CSR, M=N=8192, B=10, beta=16x16.
// R11: R10 with the prefetch-rotation bug fixed (READ current slot before
//      overwriting it with the kk+DEPTH prefetch). 6-deep W-code pipeline,
//      packed bf16 (s,-z*s) LDS, CSR fused as 17th k-slice, slim reduce.

constexpr int M_DIM = 8192;
constexpr int N_DIM = 8192;
constexpr int TN    = 512;              // N/16 scale groups per row
constexpr int BQ    = 10;               // batch (b*l)
constexpr int KSPLIT = 16;
constexpr int KRANGE = N_DIM / KSPLIT;  // 512
constexpr int KITERS = KRANGE / 32;     // 16 MFMA k-steps per wave
constexpr int RPB    = 64;              // rows per block (4 waves x 16)
constexpr int GPB    = KRANGE / 16;     // 32 scale groups per block k-range
constexpr int DEPTH  = 6;               // prefetch pairs in flight

typedef float  f32x4  __attribute__((ext_vector_type(4)));
typedef int    i32x4  __attribute__((ext_vector_type(4)));
typedef short  bf16x8 __attribute__((ext_vector_type(8)));

__device__ inline int pkbf(float a, float b) {     // -> v_cvt_pk_bf16_f32
    __hip_bfloat162 h = __float22bfloat162_rn(float2{a, b});
    int r;
    __builtin_memcpy(&r, &h, 4);
    return r;
}

__global__ __launch_bounds__(256, 4)
void spqr_mfma(const float* __restrict__ x,
               const int*   __restrict__ W,
               const int*   __restrict__ Ws,
               const int*   __restrict__ Wz,
               const float* __restrict__ Wss,
               const float* __restrict__ Wsz,
               const float* __restrict__ Wzs,
               const float* __restrict__ Wzz,
               const int*   __restrict__ row_offsets,
               const int*   __restrict__ col_ids,
               const float* __restrict__ values,
               float*       __restrict__ pws)
{
    const int t   = threadIdx.x;
    const int m0b = blockIdx.x * RPB;
    const int ks  = blockIdx.y;

    // ---- 17th slice: CSR outliers -> pws[KSPLIT] ----
    if (ks == KSPLIT) {
        const int r8 = t >> 5;              // 0..7
        const int j  = t & 31;
        float* pb = pws + (size_t)KSPLIT * (BQ * N_DIM);
        for (int rr = r8; rr < RPB; rr += 8) {
            const int m = m0b + rr;
            const int base = row_offsets[m];
            const int cnt  = row_offsets[m + 1] - base;
            float c[BQ];
            #pragma unroll
            for (int b = 0; b < BQ; ++b) c[b] = 0.f;
            for (int jj = j; jj < cnt; jj += 32) {
                const int   col = col_ids[base + jj];
                const float v   = values[base + jj];
                #pragma unroll
                for (int b = 0; b < BQ; ++b)
                    c[b] = fmaf(v, x[b * N_DIM + col], c[b]);
            }
            #pragma unroll
            for (int b = 0; b < BQ; ++b) {
                float v = c[b];
                for (int off = 16; off > 0; off >>= 1)
                    v += __shfl_xor(v, off, 32);
                c[b] = v;
            }
            if (j == 0) {
                #pragma unroll
                for (int b = 0; b < BQ; ++b)
                    pb[(size_t)b * N_DIM + m] = c[b];
            }
        }
        return;
    }

    __shared__ int ldsA[KITERS * 64 * 4];          // 16KB: bf16 A-frags
    __shared__ int ldsSZ[RPB * 33];                // 8.25KB: packed (s, -z*s) bf16x2

    const int k0 = ks * KRANGE;
    const int g0 = k0 >> 4;

    // ---- stage A-fragments: lane l of k-iter kk holds x[b=l&15][k0+kk*32+(l>>4)*8 ..+7]
    for (int idx = t; idx < KITERS * 64; idx += 256) {
        const int kk = idx >> 6, l = idx & 63;
        const int b = l & 15, koff = (kk << 5) + ((l >> 4) << 3);
        int out[4] = {0, 0, 0, 0};
        if (b < BQ) {
            const float* xp = x + b * N_DIM + k0 + koff;
            f32x4 lo = *reinterpret_cast<const f32x4*>(xp);
            f32x4 hi = *reinterpret_cast<const f32x4*>(xp + 4);
            out[0] = pkbf(lo.x, lo.y);
            out[1] = pkbf(lo.z, lo.w);
            out[2] = pkbf(hi.x, hi.y);
            out[3] = pkbf(hi.z, hi.w);
        }
        *reinterpret_cast<i32x4*>(&ldsA[idx * 4]) = *reinterpret_cast<i32x4*>(out);
    }

    // ---- stage packed first-order (s, -z*s) as bf16 pair
    for (int idx = t; idx < RPB * GPB; idx += 256) {
        const int rl = idx >> 5;                   // local row 0..63
        const int gl = idx & 31;                   // local group 0..31
        const int m = m0b + rl, g = g0 + gl;
        const int tix = (m >> 4) * TN + g;
        const float s = ((float)Ws[m * TN + g] - Wsz[tix]) * Wss[tix];
        const float z = ((float)Wz[m * TN + g] - Wzz[tix]) * Wzs[tix];
        ldsSZ[rl * 33 + gl] = pkbf(s, -z * s);
    }
    __syncthreads();

    // ---- main loop: stream W codes (6-deep pair prefetch), dequant, MFMA ----
    const int wv = t >> 6, l = t & 63;
    const int lrow = l & 15;                       // tile row
    const int lk   = l >> 4;                       // k-sub 0..3
    const int m0   = m0b + (wv << 4);
    const int* wp  = W + (size_t)(m0 + lrow) * N_DIM + k0 + (lk << 3);
    const int szrow = (wv << 4) + lrow;
    const int szk   = lk >> 1;

    f32x4 acc = {0.f, 0.f, 0.f, 0.f};
    i32x4 cbufL[DEPTH], cbufH[DEPTH];

    #pragma unroll
    for (int p = 0; p < DEPTH; ++p) {
        cbufL[p] = *reinterpret_cast<const i32x4*>(wp + p * 32);
        cbufH[p] = *reinterpret_cast<const i32x4*>(wp + p * 32 + 4);
    }

    #pragma unroll
    for (int kk = 0; kk < KITERS; ++kk) {
        // READ the current slot FIRST ...
        const i32x4 cl = cbufL[kk % DEPTH], ch = cbufH[kk % DEPTH];
        // ... THEN overwrite it with the kk+DEPTH prefetch (slot now free)
        if (kk + DEPTH < KITERS) {
            cbufL[kk % DEPTH] =
                *reinterpret_cast<const i32x4*>(wp + (kk + DEPTH) * 32);
            cbufH[kk % DEPTH] =
                *reinterpret_cast<const i32x4*>(wp + (kk + DEPTH) * 32 + 4);
        }
        const i32x4 a4 = *reinterpret_cast<const i32x4*>(&ldsA[(kk * 64 + l) * 4]);
        const int spk = ldsSZ[szrow * 33 + kk * 2 + szk];
        const float s   = __uint_as_float((unsigned)spk << 16);
        const float nzs = __uint_as_float((unsigned)spk & 0xffff0000u);
        int bw[4];
        bw[0] = pkbf(fmaf((float)cl.x, s, nzs), fmaf((float)cl.y, s, nzs));
        bw[1] = pkbf(fmaf((float)cl.z, s, nzs), fmaf((float)cl.w, s, nzs));
        bw[2] = pkbf(fmaf((float)ch.x, s, nzs), fmaf((float)ch.y, s, nzs));
        bw[3] = pkbf(fmaf((float)ch.z, s, nzs), fmaf((float)ch.w, s, nzs));
        const bf16x8 af = __builtin_bit_cast(bf16x8, a4);
        i32x4 bwv = *reinterpret_cast<i32x4*>(bw);
        const bf16x8 bf = __builtin_bit_cast(bf16x8, bwv);
        acc = __builtin_amdgcn_mfma_f32_16x16x32_bf16(af, bf, acc, 0, 0, 0);
    }

    // ---- store partials: C[row=b=(l>>4)*4+j][col=lrow] -> pws[ks][b][m0+lrow]
    float* pb = pws + (size_t)ks * (BQ * N_DIM) + (m0 + lrow);
    #pragma unroll
    for (int j = 0; j < 4; ++j) {
        const int b = (lk << 2) + j;
        if (b < BQ) pb[(size_t)b * N_DIM] = acc[j];
    }
}

__global__ __launch_bounds__(256, 4)
void spqr_reduce(const float* __restrict__ pws,
                 float*       __restrict__ y)
{
    // one thread per (b, m) output: sum 17 slices
    const int gid = blockIdx.x * 256 + threadIdx.x;       // 0 .. 10*8192-1
    if (gid >= BQ * M_DIM) return;
    const int b = gid / M_DIM;
    const int m = gid - b * M_DIM;
    const float* pp = pws + (size_t)b * N_DIM + m;
    float v = 0.f;
    #pragma unroll
    for (int ksp = 0; ksp < KSPLIT + 1; ++ksp)
        v += pp[(size_t)ksp * (BQ * N_DIM)];
    y[(size_t)b * M_DIM + m] = v;
}

extern "C" void kernel_launch(void* const* d_in, const int* in_sizes, int n_in,
                              void* d_out, int out_size, void* d_ws, size_t ws_size,
                              hipStream_t stream)
{
    const float* x    = (const float*)d_in[0];
    const int*   W    = (const int*)  d_in[1];
    const int*   Ws   = (const int*)  d_in[2];
    const int*   Wz   = (const int*)  d_in[3];
    const float* Wss  = (const float*)d_in[4];
    const float* Wsz  = (const float*)d_in[5];
    const float* Wzs  = (const float*)d_in[6];
    const float* Wzz  = (const float*)d_in[7];
    const int*   roff = (const int*)  d_in[8];
    const int*   cids = (const int*)  d_in[9];
    const float* vals = (const float*)d_in[10];
    float* yout = (float*)d_out;
    float* pws  = (float*)d_ws;                   // 17 x 10 x 8192 f32 = 5.57 MB

    dim3 grid1(M_DIM / RPB, KSPLIT + 1);          // 128 x 17 blocks
    spqr_mfma<<<grid1, dim3(256), 0, stream>>>(x, W, Ws, Wz, Wss, Wsz, Wzs, Wzz,
                                               roff, cids, vals, pws);

    dim3 grid2((BQ * M_DIM + 255) / 256);         // 320 blocks
    spqr_reduce<<<grid2, dim3(256), 0, stream>>>(pws, yout);
}